// Round 14
// baseline (579.595 us; speedup 1.0000x reference)
//
#include <hip/hip_runtime.h>

#define B_ 32
#define C_ 384
#define TX_ 512
#define TY_ 2048
#define EPS_ 1e-5f
#define LAY_ ((size_t)(36 * 1536 * 8))   // shorts per packed conv layer (442368)

typedef __attribute__((ext_vector_type(8))) short short8;
typedef __attribute__((ext_vector_type(4))) float f32x4;

#define MFMA(a, b, c) __builtin_amdgcn_mfma_f32_16x16x32_bf16(a, b, c, 0, 0, 0)

#define WAITV(N) do { asm volatile("s_waitcnt vmcnt(" #N ")"); \
                      __builtin_amdgcn_sched_barrier(0); } while (0)
#define WAITLK(N) do { asm volatile("s_waitcnt lgkmcnt(" #N ")"); \
                       __builtin_amdgcn_sched_barrier(0); } while (0)
#define SB() __builtin_amdgcn_sched_barrier(0)

typedef unsigned int u32;
// async global->LDS, 16B per lane; LDS dest = lptr + lane*16 (wave-uniform base)
__device__ __forceinline__ void gl_lds16(const void* g, void* l) {
    __builtin_amdgcn_global_load_lds(
        (const __attribute__((address_space(1))) u32*)g,
        (__attribute__((address_space(3))) u32*)l, 16, 0, 0);
}

__device__ inline unsigned short f2bf(float f) {
    union { float f; unsigned int u; } v; v.f = f;
    unsigned int r = v.u + 0x7fffu + ((v.u >> 16) & 1u);
    return (unsigned short)(r >> 16);
}
__device__ inline float bf2f(unsigned short s) {
    union { float f; unsigned int u; } v; v.u = ((unsigned int)s) << 16;
    return v.f;
}

template<bool INBF>
__device__ inline float ldx(const void* p, size_t i) {
    if constexpr (INBF) return bf2f(((const unsigned short*)p)[i]);
    else return ((const float*)p)[i];
}

// ---- pack conv weights f32 [NL][O][I][K] -> fragment-linear bf16, folding LN gamma
__global__ __launch_bounds__(256) void pack_w2(const float* cw0, const float* cw1,
                                               const float* cw2, const float* g0,
                                               const float* g1, const float* g2,
                                               unsigned short* wp) {
    int idx = blockIdx.x * 256 + threadIdx.x;
    const int NG = 6 * 36 * 384 * 4;
    if (idx >= NG) return;
    int lg = idx & 3;
    int o = (idx >> 2) % 384;
    int c = ((idx >> 2) / 384) % 36;
    int lay = (idx >> 2) / (384 * 36);
    int k = c / 12, ib = c % 12;
    int pr = lay >> 1, l = lay & 1;
    const float* cw = ((pr == 0) ? cw0 : (pr == 1) ? cw1 : cw2) + (size_t)l * C_ * C_ * 3;
    const float* g  = ((pr == 0) ? g0  : (pr == 1) ? g1  : g2)  + (size_t)l * C_;
    const int i0 = ib * 32 + lg * 8;
    short8 v;
    #pragma unroll
    for (int e = 0; e < 8; e++)
        v[e] = (short)f2bf(cw[((size_t)o * C_ + i0 + e) * 3 + k] * g[i0 + e]);
    *(short8*)&wp[(size_t)idx * 8] = v;
}

// ---- fold LN beta into conv bias (+ k=0/k=2 edge corrections)
__global__ __launch_bounds__(256) void bias_fold(
    const float* cw0, const float* cw1, const float* cw2,
    const float* be0, const float* be1, const float* be2,
    const float* cb0, const float* cb1, const float* cb2,
    float* biasT, float* bc0, float* bc2) {
    int idx = blockIdx.x * 256 + threadIdx.x;
    if (idx >= 6 * 384) return;
    int o = idx % 384, lay = idx / 384;
    int pr = lay >> 1, l = lay & 1;
    const float* cw = ((pr == 0) ? cw0 : (pr == 1) ? cw1 : cw2)
                      + (size_t)l * C_ * C_ * 3 + (size_t)o * C_ * 3;
    const float* be = ((pr == 0) ? be0 : (pr == 1) ? be1 : be2) + (size_t)l * C_;
    const float* cb = ((pr == 0) ? cb0 : (pr == 1) ? cb1 : cb2) + (size_t)l * C_;
    float s0 = 0.f, s1 = 0.f, s2 = 0.f;
    for (int i = 0; i < C_; i++) {
        const float b = be[i];
        s0 += cw[i * 3 + 0] * b; s1 += cw[i * 3 + 1] * b; s2 += cw[i * 3 + 2] * b;
    }
    biasT[idx] = cb[o] + s0 + s1 + s2;
    bc0[idx] = s0; bc2[idx] = s2;
}

// ---- pack x f32 [B][C][TX] -> fragment-linear bf16 for bmm A-operand
__global__ __launch_bounds__(256) void pack_x2(const float* x, unsigned short* xp) {
    int idx = blockIdx.x * 256 + threadIdx.x;
    const int NG = B_ * 16 * 384 * 4;
    if (idx >= NG) return;
    int lg = idx & 3;
    int c = (idx >> 2) % 384;
    int q = ((idx >> 2) / 384) % 16;
    int b = (idx >> 2) / (384 * 16);
    const float* src = x + ((size_t)b * C_ + c) * TX_ + q * 32 + lg * 8;
    short8 v;
    #pragma unroll
    for (int e = 0; e < 8; e++) v[e] = (short)f2bf(src[e]);
    *(short8*)&xp[(size_t)idx * 8] = v;
}

// ---- LN stats (mean, rstd) over C at each (b,t) of f32 [B,C,T]
__global__ __launch_bounds__(256) void ln_stats_f32(const float* x, float2* st, int T) {
    __shared__ float r1[4][64], r2[4][64];
    int b = blockIdx.y, t0 = blockIdx.x * 64;
    int tl = threadIdx.x & 63, g = threadIdx.x >> 6;
    int t = t0 + tl;
    const float* p = x + (size_t)b * C_ * T + t;
    float s = 0.f, ss = 0.f;
    for (int c = g; c < C_; c += 4) { float v = p[(size_t)c * T]; s += v; ss += v * v; }
    r1[g][tl] = s; r2[g][tl] = ss;
    __syncthreads();
    if (threadIdx.x < 64) {
        float s1 = r1[0][tl] + r1[1][tl] + r1[2][tl] + r1[3][tl];
        float s2 = r2[0][tl] + r2[1][tl] + r2[2][tl] + r2[3][tl];
        float m = s1 * (1.f / C_);
        float var = s2 * (1.f / C_) - m * m;
        st[(size_t)b * T + t0 + tl] = make_float2(m, rsqrtf(var + EPS_));
    }
}

// ---- FUSED variance predictor, 64-t tiles, 2 blocks/CU (LDS ~53 KB, VGPR<=128).
// W loaded global->REGISTER (wave-private fragment-linear stream, compiler-managed
// waits, double-buffered one step ahead). No W LDS staging at all.
template<bool INBF>
__global__ __launch_bounds__(512, 4) void fused_vp(
    const void* __restrict__ Xin, const float2* __restrict__ stin,
    const unsigned short* __restrict__ W2lay,      // L1 layer; L2 = +LAY_
    const float* __restrict__ bT,                  // [2*384] L1,L2
    const float* __restrict__ c0v, const float* __restrict__ c2v,
    const float* __restrict__ mask,
    float* __restrict__ pred, const float* __restrict__ ow,
    const float* __restrict__ obias, int T)
{
    __shared__ __align__(16) unsigned short xs[68 * 384];   // 52224 B
    __shared__ float red[132];
    __shared__ float2 st2[66];

    const int tid = threadIdx.x;
    const int b = blockIdx.y;
    const int t0 = blockIdx.x * 64;
    const int lane = tid & 63;
    const int wave = tid >> 6;
    const int lr = lane & 15, lg = lane >> 4;
    const int wm = wave * 48;

    const unsigned short* gbw = W2lay + (size_t)((wm + lr) * 4 + lg) * 8;
    const unsigned short* gbw2 = gbw + LAY_;

    // ---- stage z=(x-m)*rstd: xs rows tt=0..67 <-> input t = t0-2+tt
    {
        const int tt = 2 + lane;
        const int t = t0 + lane;
        const float2 mr = stin[(size_t)b * T + t];
        for (int i = 0; i < 6; i++) {
            const int cg = wave + 8 * i;
            const size_t base = ((size_t)b * C_ + cg * 8) * T + t;
            short8 v8;
            #pragma unroll
            for (int j = 0; j < 8; j++)
                v8[j] = (short)f2bf((ldx<INBF>(Xin, base + (size_t)j * T) - mr.x) * mr.y);
            const int ph = (cg & ~7) | ((cg ^ tt) & 7);
            *(short8*)&xs[tt * 384 + ph * 8] = v8;
        }
        if (tid < 192) {                      // halo rows 0,1,66,67
            const int q = tid / 48;
            const int tt2 = (q < 2) ? q : 64 + q;
            const int cg = tid % 48;
            const int t2 = t0 - 2 + tt2;
            short8 v8;
            if (t2 >= 0 && t2 < T) {
                const float2 mr2 = stin[(size_t)b * T + t2];
                const size_t base = ((size_t)b * C_ + cg * 8) * T + t2;
                #pragma unroll
                for (int j = 0; j < 8; j++)
                    v8[j] = (short)f2bf((ldx<INBF>(Xin, base + (size_t)j * T) - mr2.x) * mr2.y);
            } else {
                #pragma unroll
                for (int j = 0; j < 8; j++) v8[j] = 0;
            }
            const int ph = (cg & ~7) | ((cg ^ tt2) & 7);
            *(short8*)&xs[tt2 * 384 + ph * 8] = v8;
        }
    }
    __syncthreads();

    // ================= L1 K-loop: H rows tt_h 0..65 (fn 0..3 core, fn 4 halo)
    f32x4 acc[3][5];
    const f32x4 zero = {0.f, 0.f, 0.f, 0.f};
    #pragma unroll
    for (int fm = 0; fm < 3; fm++)
        #pragma unroll
        for (int fn = 0; fn < 5; fn++) acc[fm][fn] = zero;

    short8 afA[3], afB[3], bf[5];
    auto LOADW = [&](short8* d, const unsigned short* base, int c) {
        #pragma unroll
        for (int fm = 0; fm < 3; fm++)
            d[fm] = *(const short8*)(base + (size_t)c * 12288 + fm * 512);
    };
    auto LOADBF1 = [&](int c) {
        const int k = c / 12, ib = c - k * 12;
        const int cgi = ib * 4 + lg;
        #pragma unroll
        for (int fn = 0; fn < 4; fn++) {
            const int row = 1 + fn * 16 + lr + k;
            const int ph = (cgi & ~7) | ((cgi ^ row) & 7);
            bf[fn] = *(const short8*)&xs[row * 384 + ph * 8];
        }
        const int rowh = (lr == 1) ? (65 + k) : k;
        const int phh = (cgi & ~7) | ((cgi ^ rowh) & 7);
        bf[4] = *(const short8*)&xs[rowh * 384 + phh * 8];
    };
    auto FMAS1 = [&](short8* af) {
        __builtin_amdgcn_s_setprio(1);
        #pragma unroll
        for (int fm = 0; fm < 3; fm++)
            #pragma unroll
            for (int fn = 0; fn < 5; fn++)
                acc[fm][fn] = MFMA(af[fm], bf[fn], acc[fm][fn]);
        __builtin_amdgcn_s_setprio(0);
    };

    LOADW(afA, gbw, 0);
    #pragma unroll 2
    for (int c = 0; c < 36; ++c) {
        const unsigned short* nb = (c + 1 < 36) ? gbw : gbw2;  // tail preloads L2 c=0
        const int nc = (c + 1 < 36) ? c + 1 : 0;
        if ((c & 1) == 0) {
            LOADW(afB, nb, nc);
            LOADBF1(c);
            FMAS1(afA);
        } else {
            LOADW(afA, nb, nc);
            LOADBF1(c);
            FMAS1(afB);
        }
    }
    // afA now holds L2 step 0

    __syncthreads();               // xs input rows dead from here
    if (tid < 132) red[tid] = 0.f;
    __syncthreads();

    // ---- L1 epilogue pass 1: y = silu(h)*mask kept in acc; stats atomics
    #pragma unroll
    for (int fn = 0; fn < 4; fn++) {
        const int tt_h = 1 + fn * 16 + lr;
        const int t = t0 + fn * 16 + lr;
        const float mk = mask[(size_t)b * T + t];
        float s1 = 0.f, s2 = 0.f;
        #pragma unroll
        for (int fm = 0; fm < 3; fm++) {
            const int o0 = wm + fm * 16 + lg * 4;
            #pragma unroll
            for (int j = 0; j < 4; j++) {
                float h = acc[fm][fn][j] + bT[o0 + j];
                if (t == 0) h -= c0v[o0 + j];
                if (t == T - 1) h -= c2v[o0 + j];
                const float y = h * (1.f / (1.f + __expf(-h))) * mk;
                acc[fm][fn][j] = y;
                s1 += y; s2 += y * y;
            }
        }
        atomicAdd(&red[tt_h * 2], s1);
        atomicAdd(&red[tt_h * 2 + 1], s2);
    }
    {
        const int tt_h = (lr == 1) ? 65 : 0;
        const int t = t0 - 1 + tt_h;
        const bool inr = (lr < 2) && (t >= 0) && (t < T);
        const float mk = inr ? mask[(size_t)b * T + t] : 0.f;
        float s1 = 0.f, s2 = 0.f;
        #pragma unroll
        for (int fm = 0; fm < 3; fm++) {
            const int o0 = wm + fm * 16 + lg * 4;
            #pragma unroll
            for (int j = 0; j < 4; j++) {
                const float h = acc[fm][4][j] + bT[o0 + j];
                const float y = inr ? (h * (1.f / (1.f + __expf(-h))) * mk) : 0.f;
                acc[fm][4][j] = y;
                s1 += y; s2 += y * y;
            }
        }
        if (inr) {
            atomicAdd(&red[tt_h * 2], s1);
            atomicAdd(&red[tt_h * 2 + 1], s2);
        }
    }
    __syncthreads();

    if (tid < 66) {
        const float s1 = red[tid * 2], s2 = red[tid * 2 + 1];
        const float m = s1 * (1.f / C_);
        const float var = s2 * (1.f / C_) - m * m;
        st2[tid] = make_float2(m, rsqrtf(var + EPS_));
    }
    __syncthreads();

    // ---- L1 epilogue pass 2: write z2 = (y - m2)*r2 bf16 into xs
    #pragma unroll
    for (int fn = 0; fn < 4; fn++) {
        const int tt_h = 1 + fn * 16 + lr;
        const float2 mr = st2[tt_h];
        #pragma unroll
        for (int fm = 0; fm < 3; fm++) {
            ushort4 pk;
            #pragma unroll
            for (int j = 0; j < 4; j++)
                ((unsigned short*)&pk)[j] = f2bf((acc[fm][fn][j] - mr.x) * mr.y);
            const int cg = ((wm + fm * 16) >> 3) + (lg >> 1);
            const int ph = (cg & ~7) | ((cg ^ tt_h) & 7);
            *(ushort4*)&xs[tt_h * 384 + ph * 8 + (lg & 1) * 4] = pk;
        }
    }
    if (lr < 2) {
        const int tt_h = (lr == 1) ? 65 : 0;
        const float2 mr = st2[tt_h];
        #pragma unroll
        for (int fm = 0; fm < 3; fm++) {
            ushort4 pk;
            #pragma unroll
            for (int j = 0; j < 4; j++)
                ((unsigned short*)&pk)[j] = f2bf((acc[fm][4][j] - mr.x) * mr.y);
            const int cg = ((wm + fm * 16) >> 3) + (lg >> 1);
            const int ph = (cg & ~7) | ((cg ^ tt_h) & 7);
            *(ushort4*)&xs[tt_h * 384 + ph * 8 + (lg & 1) * 4] = pk;
        }
    }
    __syncthreads();

    // ================= L2 K-loop (core fn 0..3; output t = t0+tl)
    f32x4 acc2[3][4];
    #pragma unroll
    for (int fm = 0; fm < 3; fm++)
        #pragma unroll
        for (int fn = 0; fn < 4; fn++) acc2[fm][fn] = zero;

    auto LOADBF2 = [&](int c) {
        const int k = c / 12, ib = c - k * 12;
        const int cgi = ib * 4 + lg;
        #pragma unroll
        for (int fn = 0; fn < 4; fn++) {
            const int row = fn * 16 + lr + k;        // H row tt_h = tl + k
            const int ph = (cgi & ~7) | ((cgi ^ row) & 7);
            bf[fn] = *(const short8*)&xs[row * 384 + ph * 8];
        }
    };
    auto FMAS2 = [&](short8* af) {
        __builtin_amdgcn_s_setprio(1);
        #pragma unroll
        for (int fm = 0; fm < 3; fm++)
            #pragma unroll
            for (int fn = 0; fn < 4; fn++)
                acc2[fm][fn] = MFMA(af[fm], bf[fn], acc2[fm][fn]);
        __builtin_amdgcn_s_setprio(0);
    };

    #pragma unroll 2
    for (int c = 0; c < 36; ++c) {
        const int nc = (c + 1 < 36) ? c + 1 : 35;
        if ((c & 1) == 0) {
            LOADW(afB, gbw2, nc);
            LOADBF2(c);
            FMAS2(afA);
        } else {
            LOADW(afA, gbw2, nc);
            LOADBF2(c);
            FMAS2(afB);
        }
    }

    // ---- L2 epilogue: pred = (sum_o silu(h2)*mask*ow[o] + ob) * mask
    __syncthreads();
    if (tid < 64) red[tid] = 0.f;
    __syncthreads();
    #pragma unroll
    for (int fn = 0; fn < 4; fn++) {
        const int tl = fn * 16 + lr;
        const int t = t0 + tl;
        const float mk = mask[(size_t)b * T + t];
        float s1 = 0.f;
        #pragma unroll
        for (int fm = 0; fm < 3; fm++) {
            const int o0 = wm + fm * 16 + lg * 4;
            #pragma unroll
            for (int j = 0; j < 4; j++) {
                float h = acc2[fm][fn][j] + bT[384 + o0 + j];
                if (t == 0) h -= c0v[384 + o0 + j];
                if (t == T - 1) h -= c2v[384 + o0 + j];
                const float y = h * (1.f / (1.f + __expf(-h))) * mk;
                s1 += y * ow[o0 + j];
            }
        }
        atomicAdd(&red[tl], s1);
    }
    __syncthreads();
    if (tid < 64) {
        const int t = t0 + tid;
        pred[(size_t)b * T + t] = (red[tid] + obias[0]) * mask[(size_t)b * T + t];
    }
}

// ---- xe = x @ path, 128-y tiles, K chunked 4x128 in LDS (80 KB);
// pipelined bf prefetch within each chunk. Epilogue through LDS.
// (round-13 version, unchanged)
__global__ __launch_bounds__(512, 2) void bmm_ln(
    const unsigned short* __restrict__ x2, const float* __restrict__ path,
    const float* __restrict__ pitch, const float* __restrict__ energy,
    float* __restrict__ out, unsigned short* __restrict__ xebf,
    float2* __restrict__ stout, int fused)
{
    __shared__ __align__(16) char smem[81920];                  // exactly 80 KB
    unsigned short* ps = (unsigned short*)smem;                 // [128y][128t] 32 KB
    typedef unsigned short wbuf_t[2][1536];
    wbuf_t* wlds = (wbuf_t*)(smem + 32768);                     // 48 KB
    float* red = (float*)(smem + 49152);                        // 1 KB (post-K only)

    const int tid = threadIdx.x;
    const int bid = blockIdx.x;
    const int work = (bid & 7) * 64 + (bid >> 3);    // XCD-chunked swizzle (512)
    const int b = work >> 4;
    const int y0 = (work & 15) << 7;
    const int lane = tid & 63;
    const int wave = tid >> 6;
    const int lr = lane & 15, lg = lane >> 4;
    const int wm = wave * 48;

    const unsigned short* gbx = x2 + ((size_t)b * 16 * 1536 + (size_t)((wm + lr) * 4 + lg)) * 8;
    auto STAGEW = [&](int u, int buf) {
        #pragma unroll
        for (int fm = 0; fm < 3; fm++)
            gl_lds16(gbx + (size_t)u * 12288 + fm * 512, &wlds[wave][buf][fm * 512]);
    };
    STAGEW(0, 0);
    STAGEW(1, 1);

    // stage path chunk s: [128 t x 128 y] -> LDS rows y (128 bf16/row, swizzled)
    auto STAGEP = [&](int s) {
        const int yy = tid & 127;
        const int tg = tid >> 7;           // 4 groups x 32 t
        const float* pb = path + ((size_t)b * TX_ + s * 128 + tg * 32) * TY_ + y0 + yy;
        #pragma unroll
        for (int g = 0; g < 4; g++) {
            float vv[8];
            #pragma unroll
            for (int j = 0; j < 8; j++) vv[j] = pb[(size_t)(g * 8 + j) * TY_];
            short8 v8;
            #pragma unroll
            for (int j = 0; j < 8; j++) v8[j] = (short)f2bf(vv[j]);
            const int cg = tg * 4 + g;
            const int ph = (cg & ~7) | ((cg ^ yy) & 7);
            *(short8*)&ps[yy * 128 + ph * 8] = v8;
        }
    };

    f32x4 acc[3][8];
    const f32x4 zero = {0.f, 0.f, 0.f, 0.f};
    #pragma unroll
    for (int fm = 0; fm < 3; fm++)
        #pragma unroll
        for (int fn = 0; fn < 8; fn++) acc[fm][fn] = zero;

    short8 af[3], bfA[8], bfB[8];
    auto LOADAF = [&](int u) {
        #pragma unroll
        for (int fm = 0; fm < 3; fm++)
            af[fm] = *(const short8*)&wlds[wave][u & 1][fm * 512 + lane * 8];
    };
    auto LOADBF = [&](short8* dst, int uu) {
        const int cgi = uu * 4 + lg;
        #pragma unroll
        for (int fn = 0; fn < 8; fn++) {
            const int row = fn * 16 + lr;
            const int ph = (cgi & ~7) | ((cgi ^ row) & 7);
            dst[fn] = *(const short8*)&ps[row * 128 + ph * 8];
        }
    };
    auto FMAS = [&](short8* bf) {
        __builtin_amdgcn_s_setprio(1);
        #pragma unroll
        for (int fm = 0; fm < 3; fm++)
            #pragma unroll
            for (int fn = 0; fn < 8; fn++)
                acc[fm][fn] = MFMA(af[fm], bf[fn], acc[fm][fn]);
        __builtin_amdgcn_s_setprio(0);
    };

    for (int s = 0; s < 4; ++s) {
        if (s) __syncthreads();            // K-loop done with previous chunk
        STAGEP(s);
        __syncthreads();                   // chunk visible (drains vmcnt too)
        const int u0 = s * 4;
        LOADBF(bfA, 0);
        // uu = 0
        WAITV(3); LOADAF(u0); SB();
        LOADBF(bfB, 1);
        WAITLK(8); STAGEW((u0 + 2 < 16) ? u0 + 2 : 15, u0 & 1); SB();
        FMAS(bfA);
        // uu = 1
        WAITV(3); LOADAF(u0 + 1); SB();
        LOADBF(bfA, 2);
        WAITLK(8); STAGEW((u0 + 3 < 16) ? u0 + 3 : 15, (u0 + 1) & 1); SB();
        FMAS(bfB);
        // uu = 2
        WAITV(3); LOADAF(u0 + 2); SB();
        LOADBF(bfB, 3);
        WAITLK(8); STAGEW((u0 + 4 < 16) ? u0 + 4 : 15, (u0 + 2) & 1); SB();
        FMAS(bfA);
        // uu = 3 (no prefetch across the chunk barrier)
        WAITV(3); LOADAF(u0 + 3); SB();
        WAITLK(0); STAGEW((u0 + 5 < 16) ? u0 + 5 : 15, (u0 + 3) & 1); SB();
        FMAS(bfB);
    }
    WAITV(0);

    // ---- stats from acc (LDS atomics; red lives in dead wlds region)
    __syncthreads();
    if (tid < 256) red[tid] = 0.f;
    __syncthreads();
    #pragma unroll
    for (int fn = 0; fn < 8; fn++) {
        const int yl = fn * 16 + lr;
        float s1 = 0.f, s2 = 0.f;
        #pragma unroll
        for (int fm = 0; fm < 3; fm++)
            #pragma unroll
            for (int j = 0; j < 4; j++) {
                const float v = acc[fm][fn][j];
                s1 += v; s2 += v * v;
            }
        atomicAdd(&red[yl * 2], s1);
        atomicAdd(&red[yl * 2 + 1], s2);
    }

    // ---- epilogue through LDS: 4 rounds of 96-c chunks, 512B-coalesced streams
    float* psf = (float*)smem;             // 96*128 f32 = 49152 B (ps+wlds region)
    for (int r = 0; r < 4; ++r) {
        __syncthreads();
        if ((wave >> 1) == r) {            // waves 2r, 2r+1 dump their acc
            const int cbase = (wave & 1) * 48;
            #pragma unroll
            for (int fn = 0; fn < 8; fn++) {
                const int yl = fn * 16 + lr;
                #pragma unroll
                for (int fm = 0; fm < 3; fm++) {
                    const int cl = cbase + fm * 16 + lg * 4;
                    #pragma unroll
                    for (int j = 0; j < 4; j++)
                        psf[(cl + j) * 128 + yl] = acc[fm][fn][j];
                }
            }
        }
        __syncthreads();
        // stream chunk: c in [96r, 96r+96), 128 y, float4 over y
        for (int idx = tid; idx < 96 * 32; idx += 512) {
            const int cl = idx >> 5;
            const int y4 = idx & 31;
            const int c = 96 * r + cl;
            const size_t gi = ((size_t)b * C_ + c) * TY_ + y0 + y4 * 4;
            float4 v = ((float4*)&psf[cl * 128])[y4];
            if (fused) {
                const float4 p = *(const float4*)&pitch[gi];
                const float4 e = *(const float4*)&energy[gi];
                float4 o;
                o.x = v.x + p.x + e.x; o.y = v.y + p.y + e.y;
                o.z = v.z + p.z + e.z; o.w = v.w + p.w + e.w;
                *(float4*)&out[gi] = o;
                ushort4 xb;
                xb.x = f2bf(v.x); xb.y = f2bf(v.y); xb.z = f2bf(v.z); xb.w = f2bf(v.w);
                *(ushort4*)&xebf[gi] = xb;
            } else {
                *(float4*)&out[gi] = v;
            }
        }
    }
    __syncthreads();
    if (tid < 128) {
        const int y = y0 + tid;
        const float s1 = red[tid * 2], s2 = red[tid * 2 + 1];
        const float m = s1 * (1.f / C_);
        const float var = s2 * (1.f / C_) - m * m;
        stout[(size_t)b * TY_ + y] = make_float2(m, rsqrtf(var + EPS_));
    }
}

// ---- out = xe(in place) + pitch + energy   (fallback only)
__global__ __launch_bounds__(256) void add3(float4* o, const float4* p, const float4* e, int n4) {
    for (int i = blockIdx.x * 256 + threadIdx.x; i < n4; i += gridDim.x * 256) {
        float4 a = o[i], x1 = p[i], x2 = e[i];
        a.x += x1.x + x2.x; a.y += x1.y + x2.y;
        a.z += x1.z + x2.z; a.w += x1.w + x2.w;
        o[i] = a;
    }
}

extern "C" void kernel_launch(void* const* d_in, const int* in_sizes, int n_in,
                              void* d_out, int out_size, void* d_ws, size_t ws_size,
                              hipStream_t stream)
{
    const float* x      = (const float*)d_in[0];
    const float* x_mask = (const float*)d_in[1];
    const float* y_mask = (const float*)d_in[2];
    const float* pitch  = (const float*)d_in[3];
    const float* energy = (const float*)d_in[4];
    const float* path   = (const float*)d_in[5];
    const float* prm[3][6];  // [dur,pit,ene] x [lng,lnb,cw,cb,ow,ob]
    for (int p = 0; p < 3; p++)
        for (int q = 0; q < 6; q++)
            prm[p][q] = (const float*)d_in[6 + p * 6 + q];

    float* out         = (float*)d_out;
    float* dur_pred    = out + (size_t)B_ * C_ * TY_;
    float* pitch_pred  = dur_pred + B_ * TX_;
    float* energy_pred = pitch_pred + B_ * TY_;

    const size_t BCTY = (size_t)B_ * C_ * TY_;
    char* w = (char*)d_ws;
    auto alloc = [&](size_t bytes) { char* r = w; w += (bytes + 255) & ~(size_t)255; return r; };

    unsigned short* W2   = (unsigned short*)alloc(6 * LAY_ * 2);
    float* biasT         = (float*)alloc(6 * 384 * 4);
    float* bc0           = (float*)alloc(6 * 384 * 4);
    float* bc2           = (float*)alloc(6 * 384 * 4);
    float2* stA          = (float2*)alloc((size_t)B_ * TY_ * 8);  // x-stats -> xe-stats
    unsigned short* x2p  = (unsigned short*)alloc((size_t)B_ * 196608 * 2);
    size_t base_end = (size_t)(w - (char*)d_ws);
    unsigned short* xebf = (unsigned short*)alloc(BCTY * 2);
    size_t xe_end = (size_t)(w - (char*)d_ws);

    const bool haveXe = (xe_end <= ws_size);
    if (base_end > ws_size) return;

    // ---- prep
    pack_w2<<<dim3((6 * 36 * 384 * 4 + 255) / 256), 256, 0, stream>>>(
        prm[0][2], prm[1][2], prm[2][2], prm[0][0], prm[1][0], prm[2][0], W2);
    bias_fold<<<dim3(9), 256, 0, stream>>>(
        prm[0][2], prm[1][2], prm[2][2], prm[0][1], prm[1][1], prm[2][1],
        prm[0][3], prm[1][3], prm[2][3], biasT, bc0, bc2);
    pack_x2<<<dim3((B_ * 16 * 384 * 4 + 255) / 256), 256, 0, stream>>>(x, x2p);
    ln_stats_f32<<<dim3(TX_ / 64, B_), 256, 0, stream>>>(x, stA, TX_);

    // ---- duration predictor (fused pair, T = TX, input x f32)
    fused_vp<false><<<dim3(TX_ / 64, B_), 512, 0, stream>>>(
        x, stA, W2, biasT, bc0, bc2, x_mask,
        dur_pred, prm[0][4], prm[0][5], TX_);

    // ---- length regulator (writes out = xe+pitch+energy, xebf, stA)
    bmm_ln<<<dim3(512, 1, 1), 512, 0, stream>>>(
        x2p, path, pitch, energy, out, haveXe ? xebf : nullptr, stA, haveXe ? 1 : 0);

    if (haveXe) {
        fused_vp<true><<<dim3(TY_ / 64, B_), 512, 0, stream>>>(
            xebf, stA, W2 + 2 * LAY_, biasT + 2 * 384, bc0 + 2 * 384, bc2 + 2 * 384,
            y_mask, pitch_pred, prm[1][4], prm[1][5], TY_);
        fused_vp<true><<<dim3(TY_ / 64, B_), 512, 0, stream>>>(
            xebf, stA, W2 + 4 * LAY_, biasT + 4 * 384, bc0 + 4 * 384, bc2 + 4 * 384,
            y_mask, energy_pred, prm[2][4], prm[2][5], TY_);
    } else {
        fused_vp<false><<<dim3(TY_ / 64, B_), 512, 0, stream>>>(
            out, stA, W2 + 2 * LAY_, biasT + 2 * 384, bc0 + 2 * 384, bc2 + 2 * 384,
            y_mask, pitch_pred, prm[1][4], prm[1][5], TY_);
        fused_vp<false><<<dim3(TY_ / 64, B_), 512, 0, stream>>>(
            out, stA, W2 + 4 * LAY_, biasT + 4 * 384, bc0 + 4 * 384, bc2 + 4 * 384,
            y_mask, energy_pred, prm[2][4], prm[2][5], TY_);
        add3<<<dim3(2048), 256, 0, stream>>>((float4*)out, (const float4*)pitch,
                                             (const float4*)energy, B_ * C_ * TY_ / 4);
    }
}

// Round 15
// 524.412 us; speedup vs baseline: 1.1052x; 1.1052x over previous
//
#include <hip/hip_runtime.h>

#define B_ 32
#define C_ 384
#define TX_ 512
#define TY_ 2048
#define EPS_ 1e-5f
#define LAY_ ((size_t)(36 * 1536 * 8))   // shorts per packed conv layer (442368)

typedef __attribute__((ext_vector_type(8))) short short8;
typedef __attribute__((ext_vector_type(4))) float f32x4;

#define MFMA(a, b, c) __builtin_amdgcn_mfma_f32_16x16x32_bf16(a, b, c, 0, 0, 0)

#define WAITV(N) do { asm volatile("s_waitcnt vmcnt(" #N ")"); \
                      __builtin_amdgcn_sched_barrier(0); } while (0)
#define WAITLK(N) do { asm volatile("s_waitcnt lgkmcnt(" #N ")"); \
                       __builtin_amdgcn_sched_barrier(0); } while (0)
#define SB() __builtin_amdgcn_sched_barrier(0)

typedef unsigned int u32;
__device__ __forceinline__ void gl_lds16(const void* g, void* l) {
    __builtin_amdgcn_global_load_lds(
        (const __attribute__((address_space(1))) u32*)g,
        (__attribute__((address_space(3))) u32*)l, 16, 0, 0);
}

__device__ inline unsigned short f2bf(float f) {
    union { float f; unsigned int u; } v; v.f = f;
    unsigned int r = v.u + 0x7fffu + ((v.u >> 16) & 1u);
    return (unsigned short)(r >> 16);
}
__device__ inline float bf2f(unsigned short s) {
    union { float f; unsigned int u; } v; v.u = ((unsigned int)s) << 16;
    return v.f;
}

template<bool INBF>
__device__ inline float ldx(const void* p, size_t i) {
    if constexpr (INBF) return bf2f(((const unsigned short*)p)[i]);
    else return ((const float*)p)[i];
}

// ================= merged prep: pack_w2 | pack_x2 | ln_stats(x) | bias_fold
__global__ __launch_bounds__(256) void prep_all(
    const float* x,
    const float* cw0, const float* cw1, const float* cw2,
    const float* g0, const float* g1, const float* g2,
    const float* be0, const float* be1, const float* be2,
    const float* cb0, const float* cb1, const float* cb2,
    unsigned short* wp, unsigned short* xp, float2* stA,
    float* biasT, float* bc0, float* bc2)
{
    __shared__ float r1[4][64], r2[4][64];
    const int bid = blockIdx.x;
    const int tid = threadIdx.x;

    if (bid < 1296) {                                  // ---- pack_w2
        int idx = bid * 256 + tid;
        const int NG = 6 * 36 * 384 * 4;
        if (idx >= NG) return;
        int lg = idx & 3;
        int o = (idx >> 2) % 384;
        int c = ((idx >> 2) / 384) % 36;
        int lay = (idx >> 2) / (384 * 36);
        int k = c / 12, ib = c % 12;
        int pr = lay >> 1, l = lay & 1;
        const float* cw = ((pr == 0) ? cw0 : (pr == 1) ? cw1 : cw2) + (size_t)l * C_ * C_ * 3;
        const float* g  = ((pr == 0) ? g0  : (pr == 1) ? g1  : g2)  + (size_t)l * C_;
        const int i0 = ib * 32 + lg * 8;
        short8 v;
        #pragma unroll
        for (int e = 0; e < 8; e++)
            v[e] = (short)f2bf(cw[((size_t)o * C_ + i0 + e) * 3 + k] * g[i0 + e]);
        *(short8*)&wp[(size_t)idx * 8] = v;
    } else if (bid < 4368) {                           // ---- pack_x2
        int idx = (bid - 1296) * 256 + tid;
        const int NG = B_ * 16 * 384 * 4;
        if (idx >= NG) return;
        int lg = idx & 3;
        int c = (idx >> 2) % 384;
        int q = ((idx >> 2) / 384) % 16;
        int b = (idx >> 2) / (384 * 16);
        const float* src = x + ((size_t)b * C_ + c) * TX_ + q * 32 + lg * 8;
        short8 v;
        #pragma unroll
        for (int e = 0; e < 8; e++) v[e] = (short)f2bf(src[e]);
        *(short8*)&xp[(size_t)idx * 8] = v;
    } else if (bid < 4624) {                           // ---- ln_stats(x), T=TX
        const int q = bid - 4368;                      // 256 = 8 tiles x 32 b
        const int b = q >> 3, t0 = (q & 7) * 64;
        const int tl = tid & 63, g = tid >> 6;
        const int t = t0 + tl;
        const float* p = x + (size_t)b * C_ * TX_ + t;
        float s = 0.f, ss = 0.f;
        for (int c = g; c < C_; c += 4) { float v = p[(size_t)c * TX_]; s += v; ss += v * v; }
        r1[g][tl] = s; r2[g][tl] = ss;
        __syncthreads();
        if (tid < 64) {
            float s1 = r1[0][tl] + r1[1][tl] + r1[2][tl] + r1[3][tl];
            float s2 = r2[0][tl] + r2[1][tl] + r2[2][tl] + r2[3][tl];
            float m = s1 * (1.f / C_);
            float var = s2 * (1.f / C_) - m * m;
            stA[(size_t)b * TX_ + t0 + tl] = make_float2(m, rsqrtf(var + EPS_));
        }
    } else {                                           // ---- bias_fold (9 blocks)
        int idx = (bid - 4624) * 256 + tid;
        if (idx >= 6 * 384) return;
        int o = idx % 384, lay = idx / 384;
        int pr = lay >> 1, l = lay & 1;
        const float* cw = ((pr == 0) ? cw0 : (pr == 1) ? cw1 : cw2)
                          + (size_t)l * C_ * C_ * 3 + (size_t)o * C_ * 3;
        const float* be = ((pr == 0) ? be0 : (pr == 1) ? be1 : be2) + (size_t)l * C_;
        const float* cb = ((pr == 0) ? cb0 : (pr == 1) ? cb1 : cb2) + (size_t)l * C_;
        float s0 = 0.f, s1 = 0.f, s2 = 0.f;
        for (int i = 0; i < C_; i++) {
            const float b = be[i];
            s0 += cw[i * 3 + 0] * b; s1 += cw[i * 3 + 1] * b; s2 += cw[i * 3 + 2] * b;
        }
        biasT[idx] = cb[o] + s0 + s1 + s2;
        bc0[idx] = s0; bc2[idx] = s2;
    }
}

// ================= 64-t fused VP body (round-14 structure; W global->reg)
template<bool INBF>
__device__ void vp64_body(char* smem,
    const void* Xin, const float2* stin,
    const unsigned short* W2lay, const float* bT,
    const float* c0v, const float* c2v, const float* mask,
    float* pred, const float* ow, const float* obias,
    int T, int b, int t0)
{
    unsigned short* xs = (unsigned short*)smem;        // 68*384 = 52224 B
    float* red = (float*)(smem + 52224);               // 132 f
    float2* st2 = (float2*)(smem + 52224 + 544);       // 66 f2

    const int tid = threadIdx.x;
    const int lane = tid & 63;
    const int wave = tid >> 6;
    const int lr = lane & 15, lg = lane >> 4;
    const int wm = wave * 48;

    const unsigned short* gbw = W2lay + (size_t)((wm + lr) * 4 + lg) * 8;
    const unsigned short* gbw2 = gbw + LAY_;

    {   // stage z=(x-m)*rstd: rows tt=0..67 <-> t = t0-2+tt
        const int tt = 2 + lane;
        const int t = t0 + lane;
        const float2 mr = stin[(size_t)b * T + t];
        for (int i = 0; i < 6; i++) {
            const int cg = wave + 8 * i;
            const size_t base = ((size_t)b * C_ + cg * 8) * T + t;
            short8 v8;
            #pragma unroll
            for (int j = 0; j < 8; j++)
                v8[j] = (short)f2bf((ldx<INBF>(Xin, base + (size_t)j * T) - mr.x) * mr.y);
            const int ph = (cg & ~7) | ((cg ^ tt) & 7);
            *(short8*)&xs[tt * 384 + ph * 8] = v8;
        }
        if (tid < 192) {
            const int q = tid / 48;
            const int tt2 = (q < 2) ? q : 64 + q;
            const int cg = tid % 48;
            const int t2 = t0 - 2 + tt2;
            short8 v8;
            if (t2 >= 0 && t2 < T) {
                const float2 mr2 = stin[(size_t)b * T + t2];
                const size_t base = ((size_t)b * C_ + cg * 8) * T + t2;
                #pragma unroll
                for (int j = 0; j < 8; j++)
                    v8[j] = (short)f2bf((ldx<INBF>(Xin, base + (size_t)j * T) - mr2.x) * mr2.y);
            } else {
                #pragma unroll
                for (int j = 0; j < 8; j++) v8[j] = 0;
            }
            const int ph = (cg & ~7) | ((cg ^ tt2) & 7);
            *(short8*)&xs[tt2 * 384 + ph * 8] = v8;
        }
    }
    __syncthreads();

    f32x4 acc[3][5];
    const f32x4 zero = {0.f, 0.f, 0.f, 0.f};
    #pragma unroll
    for (int fm = 0; fm < 3; fm++)
        #pragma unroll
        for (int fn = 0; fn < 5; fn++) acc[fm][fn] = zero;

    short8 afA[3], afB[3], bf[5];
    auto LOADW = [&](short8* d, const unsigned short* base, int c) {
        #pragma unroll
        for (int fm = 0; fm < 3; fm++)
            d[fm] = *(const short8*)(base + (size_t)c * 12288 + fm * 512);
    };
    auto LOADBF1 = [&](int c) {
        const int k = c / 12, ib = c - k * 12;
        const int cgi = ib * 4 + lg;
        #pragma unroll
        for (int fn = 0; fn < 4; fn++) {
            const int row = 1 + fn * 16 + lr + k;
            const int ph = (cgi & ~7) | ((cgi ^ row) & 7);
            bf[fn] = *(const short8*)&xs[row * 384 + ph * 8];
        }
        const int rowh = (lr == 1) ? (65 + k) : k;
        const int phh = (cgi & ~7) | ((cgi ^ rowh) & 7);
        bf[4] = *(const short8*)&xs[rowh * 384 + phh * 8];
    };
    auto FMAS1 = [&](short8* af) {
        __builtin_amdgcn_s_setprio(1);
        #pragma unroll
        for (int fm = 0; fm < 3; fm++)
            #pragma unroll
            for (int fn = 0; fn < 5; fn++)
                acc[fm][fn] = MFMA(af[fm], bf[fn], acc[fm][fn]);
        __builtin_amdgcn_s_setprio(0);
    };

    LOADW(afA, gbw, 0);
    #pragma unroll 2
    for (int c = 0; c < 36; ++c) {
        const unsigned short* nb = (c + 1 < 36) ? gbw : gbw2;
        const int nc = (c + 1 < 36) ? c + 1 : 0;
        if ((c & 1) == 0) { LOADW(afB, nb, nc); LOADBF1(c); FMAS1(afA); }
        else              { LOADW(afA, nb, nc); LOADBF1(c); FMAS1(afB); }
    }

    __syncthreads();
    if (tid < 132) red[tid] = 0.f;
    __syncthreads();

    #pragma unroll
    for (int fn = 0; fn < 4; fn++) {
        const int tt_h = 1 + fn * 16 + lr;
        const int t = t0 + fn * 16 + lr;
        const float mk = mask[(size_t)b * T + t];
        float s1 = 0.f, s2 = 0.f;
        #pragma unroll
        for (int fm = 0; fm < 3; fm++) {
            const int o0 = wm + fm * 16 + lg * 4;
            #pragma unroll
            for (int j = 0; j < 4; j++) {
                float h = acc[fm][fn][j] + bT[o0 + j];
                if (t == 0) h -= c0v[o0 + j];
                if (t == T - 1) h -= c2v[o0 + j];
                const float y = h * (1.f / (1.f + __expf(-h))) * mk;
                acc[fm][fn][j] = y;
                s1 += y; s2 += y * y;
            }
        }
        atomicAdd(&red[tt_h * 2], s1);
        atomicAdd(&red[tt_h * 2 + 1], s2);
    }
    {
        const int tt_h = (lr == 1) ? 65 : 0;
        const int t = t0 - 1 + tt_h;
        const bool inr = (lr < 2) && (t >= 0) && (t < T);
        const float mk = inr ? mask[(size_t)b * T + t] : 0.f;
        float s1 = 0.f, s2 = 0.f;
        #pragma unroll
        for (int fm = 0; fm < 3; fm++) {
            const int o0 = wm + fm * 16 + lg * 4;
            #pragma unroll
            for (int j = 0; j < 4; j++) {
                const float h = acc[fm][4][j] + bT[o0 + j];
                const float y = inr ? (h * (1.f / (1.f + __expf(-h))) * mk) : 0.f;
                acc[fm][4][j] = y;
                s1 += y; s2 += y * y;
            }
        }
        if (inr) {
            atomicAdd(&red[tt_h * 2], s1);
            atomicAdd(&red[tt_h * 2 + 1], s2);
        }
    }
    __syncthreads();

    if (tid < 66) {
        const float s1 = red[tid * 2], s2 = red[tid * 2 + 1];
        const float m = s1 * (1.f / C_);
        const float var = s2 * (1.f / C_) - m * m;
        st2[tid] = make_float2(m, rsqrtf(var + EPS_));
    }
    __syncthreads();

    #pragma unroll
    for (int fn = 0; fn < 4; fn++) {
        const int tt_h = 1 + fn * 16 + lr;
        const float2 mr = st2[tt_h];
        #pragma unroll
        for (int fm = 0; fm < 3; fm++) {
            ushort4 pk;
            #pragma unroll
            for (int j = 0; j < 4; j++)
                ((unsigned short*)&pk)[j] = f2bf((acc[fm][fn][j] - mr.x) * mr.y);
            const int cg = ((wm + fm * 16) >> 3) + (lg >> 1);
            const int ph = (cg & ~7) | ((cg ^ tt_h) & 7);
            *(ushort4*)&xs[tt_h * 384 + ph * 8 + (lg & 1) * 4] = pk;
        }
    }
    if (lr < 2) {
        const int tt_h = (lr == 1) ? 65 : 0;
        const float2 mr = st2[tt_h];
        #pragma unroll
        for (int fm = 0; fm < 3; fm++) {
            ushort4 pk;
            #pragma unroll
            for (int j = 0; j < 4; j++)
                ((unsigned short*)&pk)[j] = f2bf((acc[fm][4][j] - mr.x) * mr.y);
            const int cg = ((wm + fm * 16) >> 3) + (lg >> 1);
            const int ph = (cg & ~7) | ((cg ^ tt_h) & 7);
            *(ushort4*)&xs[tt_h * 384 + ph * 8 + (lg & 1) * 4] = pk;
        }
    }
    __syncthreads();

    f32x4 acc2[3][4];
    #pragma unroll
    for (int fm = 0; fm < 3; fm++)
        #pragma unroll
        for (int fn = 0; fn < 4; fn++) acc2[fm][fn] = zero;

    auto LOADBF2 = [&](int c) {
        const int k = c / 12, ib = c - k * 12;
        const int cgi = ib * 4 + lg;
        #pragma unroll
        for (int fn = 0; fn < 4; fn++) {
            const int row = fn * 16 + lr + k;
            const int ph = (cgi & ~7) | ((cgi ^ row) & 7);
            bf[fn] = *(const short8*)&xs[row * 384 + ph * 8];
        }
    };
    auto FMAS2 = [&](short8* af) {
        __builtin_amdgcn_s_setprio(1);
        #pragma unroll
        for (int fm = 0; fm < 3; fm++)
            #pragma unroll
            for (int fn = 0; fn < 4; fn++)
                acc2[fm][fn] = MFMA(af[fm], bf[fn], acc2[fm][fn]);
        __builtin_amdgcn_s_setprio(0);
    };

    #pragma unroll 2
    for (int c = 0; c < 36; ++c) {
        const int nc = (c + 1 < 36) ? c + 1 : 35;
        if ((c & 1) == 0) { LOADW(afB, gbw2, nc); LOADBF2(c); FMAS2(afA); }
        else              { LOADW(afA, gbw2, nc); LOADBF2(c); FMAS2(afB); }
    }

    __syncthreads();
    if (tid < 64) red[tid] = 0.f;
    __syncthreads();
    #pragma unroll
    for (int fn = 0; fn < 4; fn++) {
        const int tl = fn * 16 + lr;
        const int t = t0 + tl;
        const float mk = mask[(size_t)b * T + t];
        float s1 = 0.f;
        #pragma unroll
        for (int fm = 0; fm < 3; fm++) {
            const int o0 = wm + fm * 16 + lg * 4;
            #pragma unroll
            for (int j = 0; j < 4; j++) {
                float h = acc2[fm][fn][j] + bT[384 + o0 + j];
                if (t == 0) h -= c0v[384 + o0 + j];
                if (t == T - 1) h -= c2v[384 + o0 + j];
                const float y = h * (1.f / (1.f + __expf(-h))) * mk;
                s1 += y * ow[o0 + j];
            }
        }
        atomicAdd(&red[tl], s1);
    }
    __syncthreads();
    if (tid < 64) {
        const int t = t0 + tid;
        pred[(size_t)b * T + t] = (red[tid] + obias[0]) * mask[(size_t)b * T + t];
    }
}

// ================= FAT kernel: blocks [0,512) = bmm (r13 body);
// blocks [512,768) = duration predictor (vp64, input x f32). Overlapped.
__global__ __launch_bounds__(512, 2) void bmm_vptx(
    const unsigned short* __restrict__ x2, const float* __restrict__ path,
    const float* __restrict__ pitch, const float* __restrict__ energy,
    float* __restrict__ out, unsigned short* __restrict__ xebf,
    float2* __restrict__ stB, int fused,
    const float* __restrict__ xf, const float2* __restrict__ stA,
    const unsigned short* __restrict__ W2, const float* __restrict__ biasT,
    const float* __restrict__ bc0, const float* __restrict__ bc2,
    const float* __restrict__ x_mask, float* __restrict__ dur_pred,
    const float* __restrict__ dow, const float* __restrict__ dob)
{
    __shared__ __align__(16) char smem[81920];

    if (blockIdx.x >= 512) {     // ---- duration predictor tile
        const int v = blockIdx.x - 512;
        vp64_body<false>(smem, xf, stA, W2, biasT, bc0, bc2, x_mask,
                         dur_pred, dow, dob, TX_, v >> 3, (v & 7) * 64);
        return;
    }

    // ---- bmm body (round-13, unchanged)
    unsigned short* ps = (unsigned short*)smem;                 // 32 KB
    typedef unsigned short wbuf_t[2][1536];
    wbuf_t* wlds = (wbuf_t*)(smem + 32768);                     // 48 KB
    float* red = (float*)(smem + 49152);

    const int tid = threadIdx.x;
    const int bid = blockIdx.x;
    const int work = (bid & 7) * 64 + (bid >> 3);    // XCD-chunked swizzle (512)
    const int b = work >> 4;
    const int y0 = (work & 15) << 7;
    const int lane = tid & 63;
    const int wave = tid >> 6;
    const int lr = lane & 15, lg = lane >> 4;
    const int wm = wave * 48;

    const unsigned short* gbx = x2 + ((size_t)b * 16 * 1536 + (size_t)((wm + lr) * 4 + lg)) * 8;
    auto STAGEW = [&](int u, int buf) {
        #pragma unroll
        for (int fm = 0; fm < 3; fm++)
            gl_lds16(gbx + (size_t)u * 12288 + fm * 512, &wlds[wave][buf][fm * 512]);
    };
    STAGEW(0, 0);
    STAGEW(1, 1);

    auto STAGEP = [&](int s) {
        const int yy = tid & 127;
        const int tg = tid >> 7;
        const float* pb = path + ((size_t)b * TX_ + s * 128 + tg * 32) * TY_ + y0 + yy;
        #pragma unroll
        for (int g = 0; g < 4; g++) {
            float vv[8];
            #pragma unroll
            for (int j = 0; j < 8; j++) vv[j] = pb[(size_t)(g * 8 + j) * TY_];
            short8 v8;
            #pragma unroll
            for (int j = 0; j < 8; j++) v8[j] = (short)f2bf(vv[j]);
            const int cg = tg * 4 + g;
            const int ph = (cg & ~7) | ((cg ^ yy) & 7);
            *(short8*)&ps[yy * 128 + ph * 8] = v8;
        }
    };

    f32x4 acc[3][8];
    const f32x4 zero = {0.f, 0.f, 0.f, 0.f};
    #pragma unroll
    for (int fm = 0; fm < 3; fm++)
        #pragma unroll
        for (int fn = 0; fn < 8; fn++) acc[fm][fn] = zero;

    short8 af[3], bfA[8], bfB[8];
    auto LOADAF = [&](int u) {
        #pragma unroll
        for (int fm = 0; fm < 3; fm++)
            af[fm] = *(const short8*)&wlds[wave][u & 1][fm * 512 + lane * 8];
    };
    auto LOADBF = [&](short8* dst, int uu) {
        const int cgi = uu * 4 + lg;
        #pragma unroll
        for (int fn = 0; fn < 8; fn++) {
            const int row = fn * 16 + lr;
            const int ph = (cgi & ~7) | ((cgi ^ row) & 7);
            dst[fn] = *(const short8*)&ps[row * 128 + ph * 8];
        }
    };
    auto FMAS = [&](short8* bf) {
        __builtin_amdgcn_s_setprio(1);
        #pragma unroll
        for (int fm = 0; fm < 3; fm++)
            #pragma unroll
            for (int fn = 0; fn < 8; fn++)
                acc[fm][fn] = MFMA(af[fm], bf[fn], acc[fm][fn]);
        __builtin_amdgcn_s_setprio(0);
    };

    for (int s = 0; s < 4; ++s) {
        if (s) __syncthreads();
        STAGEP(s);
        __syncthreads();
        const int u0 = s * 4;
        LOADBF(bfA, 0);
        WAITV(3); LOADAF(u0); SB();
        LOADBF(bfB, 1);
        WAITLK(8); STAGEW((u0 + 2 < 16) ? u0 + 2 : 15, u0 & 1); SB();
        FMAS(bfA);
        WAITV(3); LOADAF(u0 + 1); SB();
        LOADBF(bfA, 2);
        WAITLK(8); STAGEW((u0 + 3 < 16) ? u0 + 3 : 15, (u0 + 1) & 1); SB();
        FMAS(bfB);
        WAITV(3); LOADAF(u0 + 2); SB();
        LOADBF(bfB, 3);
        WAITLK(8); STAGEW((u0 + 4 < 16) ? u0 + 4 : 15, (u0 + 2) & 1); SB();
        FMAS(bfA);
        WAITV(3); LOADAF(u0 + 3); SB();
        WAITLK(0); STAGEW((u0 + 5 < 16) ? u0 + 5 : 15, (u0 + 3) & 1); SB();
        FMAS(bfB);
    }
    WAITV(0);

    __syncthreads();
    if (tid < 256) red[tid] = 0.f;
    __syncthreads();
    #pragma unroll
    for (int fn = 0; fn < 8; fn++) {
        const int yl = fn * 16 + lr;
        float s1 = 0.f, s2 = 0.f;
        #pragma unroll
        for (int fm = 0; fm < 3; fm++)
            #pragma unroll
            for (int j = 0; j < 4; j++) {
                const float v = acc[fm][fn][j];
                s1 += v; s2 += v * v;
            }
        atomicAdd(&red[yl * 2], s1);
        atomicAdd(&red[yl * 2 + 1], s2);
    }

    float* psf = (float*)smem;
    for (int r = 0; r < 4; ++r) {
        __syncthreads();
        if ((wave >> 1) == r) {
            const int cbase = (wave & 1) * 48;
            #pragma unroll
            for (int fn = 0; fn < 8; fn++) {
                const int yl = fn * 16 + lr;
                #pragma unroll
                for (int fm = 0; fm < 3; fm++) {
                    const int cl = cbase + fm * 16 + lg * 4;
                    #pragma unroll
                    for (int j = 0; j < 4; j++)
                        psf[(cl + j) * 128 + yl] = acc[fm][fn][j];
                }
            }
        }
        __syncthreads();
        for (int idx = tid; idx < 96 * 32; idx += 512) {
            const int cl = idx >> 5;
            const int y4 = idx & 31;
            const int c = 96 * r + cl;
            const size_t gi = ((size_t)b * C_ + c) * TY_ + y0 + y4 * 4;
            float4 v = ((float4*)&psf[cl * 128])[y4];
            if (fused) {
                const float4 p = *(const float4*)&pitch[gi];
                const float4 e = *(const float4*)&energy[gi];
                float4 o;
                o.x = v.x + p.x + e.x; o.y = v.y + p.y + e.y;
                o.z = v.z + p.z + e.z; o.w = v.w + p.w + e.w;
                *(float4*)&out[gi] = o;
                ushort4 xb;
                xb.x = f2bf(v.x); xb.y = f2bf(v.y); xb.z = f2bf(v.z); xb.w = f2bf(v.w);
                *(ushort4*)&xebf[gi] = xb;
            } else {
                *(float4*)&out[gi] = v;
            }
        }
    }
    __syncthreads();
    if (tid < 128) {
        const int y = y0 + tid;
        const float s1 = red[tid * 2], s2 = red[tid * 2 + 1];
        const float m = s1 * (1.f / C_);
        const float var = s2 * (1.f / C_) - m * m;
        stB[(size_t)b * TY_ + y] = make_float2(m, rsqrtf(var + EPS_));
    }
}

// ================= 128-t fused VP (round-13 structure) with z = {pitch, energy}
template<bool INBF>
__global__ __launch_bounds__(512, 2) void vp128(
    const void* __restrict__ Xin, const float2* __restrict__ stin,
    const unsigned short* __restrict__ W2full, const float* __restrict__ biasT,
    const float* __restrict__ bc0f, const float* __restrict__ bc2f,
    const float* __restrict__ mask,
    float* __restrict__ pred1, float* __restrict__ pred2,
    const float* __restrict__ ow1, const float* __restrict__ ow2,
    const float* __restrict__ ob1, const float* __restrict__ ob2, int T)
{
    __shared__ __align__(16) unsigned short xs[132 * 384];
    __shared__ __align__(16) unsigned short wlds[8][2][1536];
    __shared__ float red[260];
    __shared__ float2 st2[130];

    const int z = blockIdx.z;
    const unsigned short* W2lay = W2full + (size_t)(2 + 2 * z) * LAY_;
    const float* bT  = biasT + (2 + 2 * z) * 384;
    const float* c0v = bc0f  + (2 + 2 * z) * 384;
    const float* c2v = bc2f  + (2 + 2 * z) * 384;
    float* pred = z ? pred2 : pred1;
    const float* ow = z ? ow2 : ow1;
    const float* obias = z ? ob2 : ob1;

    const int tid = threadIdx.x;
    const int b = blockIdx.y;
    const int t0 = blockIdx.x * 128;
    const int lane = tid & 63;
    const int wave = tid >> 6;
    const int lr = lane & 15, lg = lane >> 4;
    const int wm = wave * 48;

    const unsigned short* gbw = W2lay + (size_t)((wm + lr) * 4 + lg) * 8;
    const unsigned short* gbw2 = gbw + LAY_;
    auto STAGE = [&](const unsigned short* base, int c, int buf) {
        #pragma unroll
        for (int fm = 0; fm < 3; fm++)
            gl_lds16(base + (size_t)c * 12288 + fm * 512, &wlds[wave][buf][fm * 512]);
    };
    STAGE(gbw, 0, 0);
    STAGE(gbw, 1, 1);

    {
        const int tl = tid & 127;
        const int tt = 2 + tl;
        const int t = t0 + tl;
        const float2 mr = stin[(size_t)b * T + t];
        const int cg0 = (tid >> 7) * 12;
        for (int i = 0; i < 12; i++) {
            const int cg = cg0 + i;
            const size_t base = ((size_t)b * C_ + cg * 8) * T + t;
            short8 v8;
            #pragma unroll
            for (int j = 0; j < 8; j++)
                v8[j] = (short)f2bf((ldx<INBF>(Xin, base + (size_t)j * T) - mr.x) * mr.y);
            const int ph = (cg & ~7) | ((cg ^ tt) & 7);
            *(short8*)&xs[tt * 384 + ph * 8] = v8;
        }
        if (tid < 192) {
            const int q = tid / 48;
            const int tt2 = (q < 2) ? q : 128 + q;
            const int cg = tid % 48;
            const int t2 = t0 - 2 + tt2;
            short8 v8;
            if (t2 >= 0 && t2 < T) {
                const float2 mr2 = stin[(size_t)b * T + t2];
                const size_t base = ((size_t)b * C_ + cg * 8) * T + t2;
                #pragma unroll
                for (int j = 0; j < 8; j++)
                    v8[j] = (short)f2bf((ldx<INBF>(Xin, base + (size_t)j * T) - mr2.x) * mr2.y);
            } else {
                #pragma unroll
                for (int j = 0; j < 8; j++) v8[j] = 0;
            }
            const int ph = (cg & ~7) | ((cg ^ tt2) & 7);
            *(short8*)&xs[tt2 * 384 + ph * 8] = v8;
        }
    }
    __syncthreads();

    f32x4 acc[3][9];
    const f32x4 zero = {0.f, 0.f, 0.f, 0.f};
    #pragma unroll
    for (int fm = 0; fm < 3; fm++)
        #pragma unroll
        for (int fn = 0; fn < 9; fn++) acc[fm][fn] = zero;

    short8 af[3], bfA[9], bfB[9];
    auto LOADBF1 = [&](short8* dst, int c) {
        const int k = c / 12, ib = c - k * 12;
        const int cgi = ib * 4 + lg;
        #pragma unroll
        for (int fn = 0; fn < 8; fn++) {
            const int row = 1 + fn * 16 + lr + k;
            const int ph = (cgi & ~7) | ((cgi ^ row) & 7);
            dst[fn] = *(const short8*)&xs[row * 384 + ph * 8];
        }
        const int rowh = (lr == 1) ? (129 + k) : k;
        const int phh = (cgi & ~7) | ((cgi ^ rowh) & 7);
        dst[8] = *(const short8*)&xs[rowh * 384 + phh * 8];
    };
    auto LOADAF = [&](int c) {
        #pragma unroll
        for (int fm = 0; fm < 3; fm++)
            af[fm] = *(const short8*)&wlds[wave][c & 1][fm * 512 + lane * 8];
    };
    auto FMAS1 = [&](short8* bf) {
        __builtin_amdgcn_s_setprio(1);
        #pragma unroll
        for (int fm = 0; fm < 3; fm++)
            #pragma unroll
            for (int fn = 0; fn < 9; fn++)
                acc[fm][fn] = MFMA(af[fm], bf[fn], acc[fm][fn]);
        __builtin_amdgcn_s_setprio(0);
    };
    auto STAGE1 = [&](int s) {
        if (s + 2 < 36) STAGE(gbw, s + 2, s & 1);
        else            STAGE(gbw2, s - 34, s & 1);
    };

    LOADBF1(bfA, 0);
    for (int c = 0; c < 36; c += 2) {
        WAITV(3);
        LOADAF(c); SB();
        LOADBF1(bfB, c + 1);
        WAITLK(9);
        STAGE1(c); SB();
        FMAS1(bfA);
        WAITV(3);
        LOADAF(c + 1); SB();
        LOADBF1(bfA, (c + 2 < 36) ? c + 2 : 35);
        WAITLK(9);
        STAGE1(c + 1); SB();
        FMAS1(bfB);
    }

    __syncthreads();
    if (tid < 260) red[tid] = 0.f;
    __syncthreads();

    #pragma unroll
    for (int fn = 0; fn < 8; fn++) {
        const int tt_h = 1 + fn * 16 + lr;
        const int t = t0 + fn * 16 + lr;
        const float mk = mask[(size_t)b * T + t];
        float s1 = 0.f, s2 = 0.f;
        #pragma unroll
        for (int fm = 0; fm < 3; fm++) {
            const int o0 = wm + fm * 16 + lg * 4;
            #pragma unroll
            for (int j = 0; j < 4; j++) {
                float h = acc[fm][fn][j] + bT[o0 + j];
                if (t == 0) h -= c0v[o0 + j];
                if (t == T - 1) h -= c2v[o0 + j];
                const float y = h * (1.f / (1.f + __expf(-h))) * mk;
                acc[fm][fn][j] = y;
                s1 += y; s2 += y * y;
            }
        }
        atomicAdd(&red[tt_h * 2], s1);
        atomicAdd(&red[tt_h * 2 + 1], s2);
    }
    {
        const int tt_h = (lr == 1) ? 129 : 0;
        const int t = t0 - 1 + tt_h;
        const bool inr = (lr < 2) && (t >= 0) && (t < T);
        const float mk = inr ? mask[(size_t)b * T + t] : 0.f;
        float s1 = 0.f, s2 = 0.f;
        #pragma unroll
        for (int fm = 0; fm < 3; fm++) {
            const int o0 = wm + fm * 16 + lg * 4;
            #pragma unroll
            for (int j = 0; j < 4; j++) {
                const float h = acc[fm][8][j] + bT[o0 + j];
                const float y = inr ? (h * (1.f / (1.f + __expf(-h))) * mk) : 0.f;
                acc[fm][8][j] = y;
                s1 += y; s2 += y * y;
            }
        }
        if (inr) {
            atomicAdd(&red[tt_h * 2], s1);
            atomicAdd(&red[tt_h * 2 + 1], s2);
        }
    }
    __syncthreads();

    if (tid < 130) {
        const float s1 = red[tid * 2], s2 = red[tid * 2 + 1];
        const float m = s1 * (1.f / C_);
        const float var = s2 * (1.f / C_) - m * m;
        st2[tid] = make_float2(m, rsqrtf(var + EPS_));
    }
    __syncthreads();

    #pragma unroll
    for (int fn = 0; fn < 8; fn++) {
        const int tt_h = 1 + fn * 16 + lr;
        const float2 mr = st2[tt_h];
        #pragma unroll
        for (int fm = 0; fm < 3; fm++) {
            ushort4 pk;
            #pragma unroll
            for (int j = 0; j < 4; j++)
                ((unsigned short*)&pk)[j] = f2bf((acc[fm][fn][j] - mr.x) * mr.y);
            const int cg = ((wm + fm * 16) >> 3) + (lg >> 1);
            const int ph = (cg & ~7) | ((cg ^ tt_h) & 7);
            *(ushort4*)&xs[tt_h * 384 + ph * 8 + (lg & 1) * 4] = pk;
        }
    }
    if (lr < 2) {
        const int tt_h = (lr == 1) ? 129 : 0;
        const float2 mr = st2[tt_h];
        #pragma unroll
        for (int fm = 0; fm < 3; fm++) {
            ushort4 pk;
            #pragma unroll
            for (int j = 0; j < 4; j++)
                ((unsigned short*)&pk)[j] = f2bf((acc[fm][8][j] - mr.x) * mr.y);
            const int cg = ((wm + fm * 16) >> 3) + (lg >> 1);
            const int ph = (cg & ~7) | ((cg ^ tt_h) & 7);
            *(ushort4*)&xs[tt_h * 384 + ph * 8 + (lg & 1) * 4] = pk;
        }
    }
    __syncthreads();

    f32x4 acc2[3][8];
    #pragma unroll
    for (int fm = 0; fm < 3; fm++)
        #pragma unroll
        for (int fn = 0; fn < 8; fn++) acc2[fm][fn] = zero;

    auto LOADBF2 = [&](short8* dst, int c) {
        const int k = c / 12, ib = c - k * 12;
        const int cgi = ib * 4 + lg;
        #pragma unroll
        for (int fn = 0; fn < 8; fn++) {
            const int row = fn * 16 + lr + k;
            const int ph = (cgi & ~7) | ((cgi ^ row) & 7);
            dst[fn] = *(const short8*)&xs[row * 384 + ph * 8];
        }
    };
    auto FMAS2 = [&](short8* bf) {
        __builtin_amdgcn_s_setprio(1);
        #pragma unroll
        for (int fm = 0; fm < 3; fm++)
            #pragma unroll
            for (int fn = 0; fn < 8; fn++)
                acc2[fm][fn] = MFMA(af[fm], bf[fn], acc2[fm][fn]);
        __builtin_amdgcn_s_setprio(0);
    };
    auto STAGE2 = [&](int s) {
        STAGE(gbw2, (s + 2 < 36) ? s + 2 : 35, s & 1);
    };

    LOADBF2(bfA, 0);
    for (int c = 0; c < 36; c += 2) {
        WAITV(3);
        LOADAF(c); SB();
        LOADBF2(bfB, c + 1);
        WAITLK(8);
        STAGE2(c); SB();
        FMAS2(bfA);
        WAITV(3);
        LOADAF(c + 1); SB();
        LOADBF2(bfA, (c + 2 < 36) ? c + 2 : 35);
        WAITLK(8);
        STAGE2(c + 1); SB();
        FMAS2(bfB);
    }

    __syncthreads();
    if (tid < 128) red[tid] = 0.f;
    __syncthreads();
    #pragma unroll
    for (int fn = 0; fn < 8; fn++) {
        const int tl = fn * 16 + lr;
        const int t = t0 + tl;
        const float mk = mask[(size_t)b * T + t];
        float s1 = 0.f;
        #pragma unroll
        for (int fm = 0; fm < 3; fm++) {
            const int o0 = wm + fm * 16 + lg * 4;
            #pragma unroll
            for (int j = 0; j < 4; j++) {
                float h = acc2[fm][fn][j] + bT[384 + o0 + j];
                if (t == 0) h -= c0v[384 + o0 + j];
                if (t == T - 1) h -= c2v[384 + o0 + j];
                const float y = h * (1.f / (1.f + __expf(-h))) * mk;
                s1 += y * ow[o0 + j];
            }
        }
        atomicAdd(&red[tl], s1);
    }
    __syncthreads();
    if (tid < 128) {
        const int t = t0 + tid;
        pred[(size_t)b * T + t] = (red[tid] + obias[0]) * mask[(size_t)b * T + t];
    }
}

// ---- out = xe(in place) + pitch + energy   (fallback only)
__global__ __launch_bounds__(256) void add3(float4* o, const float4* p, const float4* e, int n4) {
    for (int i = blockIdx.x * 256 + threadIdx.x; i < n4; i += gridDim.x * 256) {
        float4 a = o[i], x1 = p[i], x2 = e[i];
        a.x += x1.x + x2.x; a.y += x1.y + x2.y;
        a.z += x1.z + x2.z; a.w += x1.w + x2.w;
        o[i] = a;
    }
}

extern "C" void kernel_launch(void* const* d_in, const int* in_sizes, int n_in,
                              void* d_out, int out_size, void* d_ws, size_t ws_size,
                              hipStream_t stream)
{
    const float* x      = (const float*)d_in[0];
    const float* x_mask = (const float*)d_in[1];
    const float* y_mask = (const float*)d_in[2];
    const float* pitch  = (const float*)d_in[3];
    const float* energy = (const float*)d_in[4];
    const float* path   = (const float*)d_in[5];
    const float* prm[3][6];
    for (int p = 0; p < 3; p++)
        for (int q = 0; q < 6; q++)
            prm[p][q] = (const float*)d_in[6 + p * 6 + q];

    float* out         = (float*)d_out;
    float* dur_pred    = out + (size_t)B_ * C_ * TY_;
    float* pitch_pred  = dur_pred + B_ * TX_;
    float* energy_pred = pitch_pred + B_ * TY_;

    const size_t BCTY = (size_t)B_ * C_ * TY_;
    char* w = (char*)d_ws;
    auto alloc = [&](size_t bytes) { char* r = w; w += (bytes + 255) & ~(size_t)255; return r; };

    unsigned short* W2   = (unsigned short*)alloc(6 * LAY_ * 2);
    float* biasT         = (float*)alloc(6 * 384 * 4);
    float* bc0           = (float*)alloc(6 * 384 * 4);
    float* bc2           = (float*)alloc(6 * 384 * 4);
    float2* stA          = (float2*)alloc((size_t)B_ * TY_ * 8);  // x stats
    float2* stB          = (float2*)alloc((size_t)B_ * TY_ * 8);  // xe stats
    unsigned short* x2p  = (unsigned short*)alloc((size_t)B_ * 196608 * 2);
    size_t base_end = (size_t)(w - (char*)d_ws);
    unsigned short* xebf = (unsigned short*)alloc(BCTY * 2);
    size_t xe_end = (size_t)(w - (char*)d_ws);

    const bool haveXe = (xe_end <= ws_size);
    if (base_end > ws_size) return;

    // ---- merged prep (pack_w2 | pack_x2 | ln_stats | bias_fold)
    prep_all<<<dim3(4633), 256, 0, stream>>>(
        x, prm[0][2], prm[1][2], prm[2][2], prm[0][0], prm[1][0], prm[2][0],
        prm[0][1], prm[1][1], prm[2][1], prm[0][3], prm[1][3], prm[2][3],
        W2, x2p, stA, biasT, bc0, bc2);

    // ---- fat dispatch: bmm (512 blocks) + duration predictor (256 blocks)
    bmm_vptx<<<dim3(768), 512, 0, stream>>>(
        x2p, path, pitch, energy, out, haveXe ? xebf : nullptr, stB,
        haveXe ? 1 : 0, x, stA, W2, biasT, bc0, bc2, x_mask,
        dur_pred, prm[0][4], prm[0][5]);

    // ---- pitch + energy predictors in one dispatch (z = 0/1)
    if (haveXe) {
        vp128<true><<<dim3(TY_ / 128, B_, 2), 512, 0, stream>>>(
            xebf, stB, W2, biasT, bc0, bc2, y_mask,
            pitch_pred, energy_pred, prm[1][4], prm[2][4], prm[1][5], prm[2][5], TY_);
    } else {
        vp128<false><<<dim3(TY_ / 128, B_, 2), 512, 0, stream>>>(
            out, stB, W2, biasT, bc0, bc2, y_mask,
            pitch_pred, energy_pred, prm[1][4], prm[2][4], prm[1][5], prm[2][5], TY_);
        add3<<<dim3(2048), 256, 0, stream>>>((float4*)out, (const float4*)pitch,
                                             (const float4*)energy, B_ * C_ * TY_ / 4);
    }
}